// Round 1
// baseline (3331.161 us; speedup 1.0000x reference)
//
#include <hip/hip_runtime.h>
#include <math.h>

// Layer_67637144978060: y = x + out + 0.03*(reads @ Wp_r^T);  W_new = S_T
// where out = rmsnorm(x,g), v = out@Wp_w^T, wk_t = out_{t-1},
// S_0 = W, reads_t = S_t @ out_t, S_{t+1} = e^lg * S_t + v_t (x) wk_t.
// Chunked (C=256): parallel {rmsnorm, v, intra-chunk scores, scores@v},
// then 16-step scan {R1: reads += e^{lg*tc} * out_chunk @ S^T ; update S}.
// Round 1: pure f32 tiled GEMMs (correctness baseline). MFMA comes later.

#define TPB 256

enum { M_PLAIN = 0, M_SCORES = 1, M_R1ACC = 2, M_UPDATE = 3, M_FINAL = 4 };

struct GP {
  const float* A; const float* B; float* C;
  const float* X; const float* O;   // extras for M_FINAL (x and out)
  const float* decay;               // device scalar
  int M, N, K;
  int lda, ldb, ldc;
  long sAb, sBb, sCb, sCk;          // per-batch strides (+ per-chunk C stride)
  int NC;                           // chunks folded into blockIdx.z
  int aOff0, aStep;                 // A storage-row offset: aOff0 + chunk*aStep
  int bOff0, bStep;                 // B storage-row offset; rows < 0 read as zero (wk shift)
};

// C[m,n] = sum_k A[m,k]*B[n,k]  (AMAJ=0: A[m][k], =1: A[k][m]; BMAJ=0: B[n][k], =1: B[k][n])
template<int AMAJ, int BMAJ, int MODE, int BM, int BN, int TM, int TN>
__global__ __launch_bounds__(TPB) void gemm_k(GP p) {
  constexpr int BK = 16;
  __shared__ float As[BK][BM];
  __shared__ float Bs[BK][BN];
  const int tid = threadIdx.x;
  const int z = blockIdx.z;
  const int b = z / p.NC, ch = z % p.NC;
  const int m0 = blockIdx.x * BM, n0 = blockIdx.y * BN;
  const float lg = -log1pf(expf(-p.decay[0]));   // log(sigmoid(decay))
  const float* Ab = p.A + (long)b * p.sAb;
  const float* Bb = p.B + (long)b * p.sBb;
  float* Cb = p.C + (long)b * p.sCb + (long)ch * p.sCk;
  const int aRow0 = p.aOff0 + ch * p.aStep;
  const int bRow0 = p.bOff0 + ch * p.bStep;

  float acc[TM][TN];
#pragma unroll
  for (int i = 0; i < TM; i++)
#pragma unroll
    for (int j = 0; j < TN; j++) acc[i][j] = 0.f;

  const int tn = tid % (BN / TN);
  const int tm = tid / (BN / TN);

  for (int k0 = 0; k0 < p.K; k0 += BK) {
    // ---- stage A tile into As[kk][m] ----
    if (AMAJ == 0) {
      for (int idx = tid; idx < BM * BK / 4; idx += TPB) {
        int k4 = idx % (BK / 4); int m = idx / (BK / 4);
        const float4 vv = *(const float4*)&Ab[(long)(aRow0 + m0 + m) * p.lda + k0 + k4 * 4];
        As[k4 * 4 + 0][m] = vv.x; As[k4 * 4 + 1][m] = vv.y;
        As[k4 * 4 + 2][m] = vv.z; As[k4 * 4 + 3][m] = vv.w;
      }
    } else {
      for (int idx = tid; idx < BM * BK / 4; idx += TPB) {
        int m4 = idx % (BM / 4); int kk = idx / (BM / 4);
        float4 vv = *(const float4*)&Ab[(long)(aRow0 + k0 + kk) * p.lda + m0 + m4 * 4];
        if constexpr (MODE == M_UPDATE) {   // per-k decay weight e^{lg*(K-1-k)}
          float ks = expf(lg * (float)(p.K - 1 - (k0 + kk)));
          vv.x *= ks; vv.y *= ks; vv.z *= ks; vv.w *= ks;
        }
        *(float4*)&As[kk][m4 * 4] = vv;
      }
    }
    // ---- stage B tile into Bs[kk][n] ----
    if (BMAJ == 0) {
      for (int idx = tid; idx < BN * BK / 4; idx += TPB) {
        int k4 = idx % (BK / 4); int n = idx / (BK / 4);
        int srow = bRow0 + n0 + n;
        float4 vv = make_float4(0.f, 0.f, 0.f, 0.f);
        if (srow >= 0) vv = *(const float4*)&Bb[(long)srow * p.ldb + k0 + k4 * 4];
        Bs[k4 * 4 + 0][n] = vv.x; Bs[k4 * 4 + 1][n] = vv.y;
        Bs[k4 * 4 + 2][n] = vv.z; Bs[k4 * 4 + 3][n] = vv.w;
      }
    } else {
      for (int idx = tid; idx < BN * BK / 4; idx += TPB) {
        int n4 = idx % (BN / 4); int kk = idx / (BN / 4);
        int srow = bRow0 + k0 + kk;
        float4 vv = make_float4(0.f, 0.f, 0.f, 0.f);
        if (srow >= 0) vv = *(const float4*)&Bb[(long)srow * p.ldb + n0 + n4 * 4];
        *(float4*)&Bs[kk][n4 * 4] = vv;
      }
    }
    __syncthreads();
#pragma unroll
    for (int kk = 0; kk < BK; kk++) {
      float a[TM], bv[TN];
#pragma unroll
      for (int i = 0; i < TM; i += 4) *(float4*)&a[i] = *(const float4*)&As[kk][tm * TM + i];
#pragma unroll
      for (int j = 0; j < TN; j += 4) *(float4*)&bv[j] = *(const float4*)&Bs[kk][tn * TN + j];
#pragma unroll
      for (int i = 0; i < TM; i++)
#pragma unroll
        for (int j = 0; j < TN; j++) acc[i][j] += a[i] * bv[j];
    }
    __syncthreads();
  }

  // ---- epilogue ----
#pragma unroll
  for (int i = 0; i < TM; i++) {
    const int m = m0 + tm * TM + i;
#pragma unroll
    for (int j = 0; j < TN; j++) {
      const int n = n0 + tn * TN + j;
      const long ci = (long)m * p.ldc + n;
      const float vacc = acc[i][j];
      if constexpr (MODE == M_PLAIN) {
        Cb[ci] = vacc;
      } else if constexpr (MODE == M_SCORES) {
        Cb[ci] = (n < m) ? vacc * expf(lg * (float)(m - 1 - n)) : 0.f;
      } else if constexpr (MODE == M_R1ACC) {
        Cb[ci] += expf(lg * (float)m) * vacc;
      } else if constexpr (MODE == M_UPDATE) {
        Cb[ci] = expf(lg * (float)p.K) * Cb[ci] + vacc;
      } else if constexpr (MODE == M_FINAL) {
        const float* Xb = p.X + (long)b * p.sCb;
        const float* Ob = p.O + (long)b * p.sCb;
        Cb[ci] = Xb[ci] + Ob[ci] + 0.03f * vacc;
      }
    }
  }
}

// one block per row; blockDim = D/4 (D=1024 -> 256 thr), each thread one float4
__global__ __launch_bounds__(256) void rmsnorm_k(const float* __restrict__ x,
                                                 const float* __restrict__ g,
                                                 float* __restrict__ out, int D) {
  const long row = blockIdx.x;
  const float* xr = x + row * (long)D;
  float* orow = out + row * (long)D;
  const int t = threadIdx.x;
  const float4 xv = *(const float4*)&xr[t * 4];
  float ss = xv.x * xv.x + xv.y * xv.y + xv.z * xv.z + xv.w * xv.w;
  for (int off = 32; off; off >>= 1) ss += __shfl_down(ss, off);
  __shared__ float sred[4];
  if ((t & 63) == 0) sred[t >> 6] = ss;
  __syncthreads();
  const float tot = sred[0] + sred[1] + sred[2] + sred[3];
  const float scale = rsqrtf(tot / (float)D + 1e-6f);
  const float4 gv = *(const float4*)&g[t * 4];
  float4 ov;
  ov.x = xv.x * scale * gv.x; ov.y = xv.y * scale * gv.y;
  ov.z = xv.z * scale * gv.z; ov.w = xv.w * scale * gv.w;
  *(float4*)&orow[t * 4] = ov;
}

extern "C" void kernel_launch(void* const* d_in, const int* in_sizes, int n_in,
                              void* d_out, int out_size, void* d_ws, size_t ws_size,
                              hipStream_t stream) {
  const float* x     = (const float*)d_in[0];
  const float* W     = (const float*)d_in[1];
  const float* g     = (const float*)d_in[2];
  const float* Wpw   = (const float*)d_in[3];
  const float* Wpr   = (const float*)d_in[4];
  const float* decay = (const float*)d_in[5];

  const int D  = in_sizes[2];                 // 1024
  const int Bn = in_sizes[1] / (D * D);       // 4
  const int T  = in_sizes[0] / (Bn * D);      // 4096
  const int C  = 256, NC = T / C;             // 16 chunks
  const long TD = (long)T * D, DD = (long)D * D;

  float* out    = (float*)d_ws;               // [B,T,D]
  float* v      = out + Bn * TD;              // [B,T,D]
  float* reads  = v + Bn * TD;                // [B,T,D]
  float* scores = reads + Bn * TD;            // [B,NC,C,C]
  float* y = (float*)d_out;                   // [B,T,D]
  float* S = y + Bn * TD;                     // [B,D,D]  (== W_new output region)

  // 1) out = rmsnorm(x, g)
  rmsnorm_k<<<Bn * T, D / 4, 0, stream>>>(x, g, out, D);
  // 2) S = W
  hipMemcpyAsync(S, W, sizeof(float) * Bn * DD, hipMemcpyDeviceToDevice, stream);

  // 3) v = out @ Wp_w^T      (NT, plain)
  {
    GP p{}; p.decay = decay;
    p.A = out; p.lda = D; p.sAb = TD; p.aOff0 = 0; p.aStep = 0;
    p.B = Wpw; p.ldb = D; p.sBb = 0;  p.bOff0 = 0; p.bStep = 0;
    p.C = v;   p.ldc = D; p.sCb = TD; p.sCk = 0;
    p.M = T; p.N = D; p.K = D; p.NC = 1;
    gemm_k<0, 0, M_PLAIN, 128, 128, 8, 8><<<dim3(T / 128, D / 128, Bn), TPB, 0, stream>>>(p);
  }
  // 4) intra-chunk scores, all chunks in one launch (NT + mask/decay epilogue)
  {
    GP p{}; p.decay = decay;
    p.A = out;    p.lda = D; p.sAb = TD; p.aOff0 = 0;  p.aStep = C;
    p.B = out;    p.ldb = D; p.sBb = TD; p.bOff0 = -1; p.bStep = C;   // wk = out shifted
    p.C = scores; p.ldc = C; p.sCb = (long)NC * C * C; p.sCk = (long)C * C;
    p.M = C; p.N = C; p.K = D; p.NC = NC;
    gemm_k<0, 0, M_SCORES, 128, 128, 8, 8><<<dim3(C / 128, C / 128, Bn * NC), TPB, 0, stream>>>(p);
  }
  // 5) reads = scores @ v_chunk, all chunks (NN, plain write)
  {
    GP p{}; p.decay = decay;
    p.A = scores; p.lda = C; p.sAb = (long)NC * C * C; p.aOff0 = 0; p.aStep = C;
    p.B = v;      p.ldb = D; p.sBb = TD; p.bOff0 = 0; p.bStep = C;
    p.C = reads;  p.ldc = D; p.sCb = TD; p.sCk = (long)C * D;
    p.M = C; p.N = D; p.K = C; p.NC = NC;
    gemm_k<0, 1, M_PLAIN, 128, 128, 8, 8><<<dim3(C / 128, D / 128, Bn * NC), TPB, 0, stream>>>(p);
  }
  // 6) serial scan over chunks: inter-chunk read then state update
  for (int k = 0; k < NC; k++) {
    const int t0 = k * C;
    { // reads[t0+tc] += e^{lg*tc} * out_chunk @ S^T   (NT, accumulate)
      GP p{}; p.decay = decay;
      p.A = out; p.lda = D; p.sAb = TD; p.aOff0 = t0; p.aStep = 0;
      p.B = S;   p.ldb = D; p.sBb = DD; p.bOff0 = 0;  p.bStep = 0;
      p.C = reads + (long)t0 * D; p.ldc = D; p.sCb = TD; p.sCk = 0;
      p.M = C; p.N = D; p.K = D; p.NC = 1;
      gemm_k<0, 0, M_R1ACC, 64, 64, 4, 4><<<dim3(C / 64, D / 64, Bn), TPB, 0, stream>>>(p);
    }
    { // S = e^{lg*C} * S + sum_k e^{lg*(C-1-k)} v_k (x) wk_k   (TN, in-place)
      GP p{}; p.decay = decay;
      p.A = v;   p.lda = D; p.sAb = TD; p.aOff0 = t0;     p.aStep = 0;
      p.B = out; p.ldb = D; p.sBb = TD; p.bOff0 = t0 - 1; p.bStep = 0;
      p.C = S;   p.ldc = D; p.sCb = DD; p.sCk = 0;
      p.M = D; p.N = D; p.K = C; p.NC = 1;
      gemm_k<1, 1, M_UPDATE, 128, 128, 8, 8><<<dim3(D / 128, D / 128, Bn), TPB, 0, stream>>>(p);
    }
  }
  // 7) y = x + out + 0.03 * reads @ Wp_r^T   (NT + final epilogue)
  {
    GP p{}; p.decay = decay;
    p.A = reads; p.lda = D; p.sAb = TD; p.aOff0 = 0; p.aStep = 0;
    p.B = Wpr;   p.ldb = D; p.sBb = 0;  p.bOff0 = 0; p.bStep = 0;
    p.C = y;     p.ldc = D; p.sCb = TD; p.sCk = 0;
    p.X = x; p.O = out;
    p.M = T; p.N = D; p.K = D; p.NC = 1;
    gemm_k<0, 0, M_FINAL, 128, 128, 8, 8><<<dim3(T / 128, D / 128, Bn), TPB, 0, stream>>>(p);
  }
}

// Round 5
// 745.328 us; speedup vs baseline: 4.4694x; 4.4694x over previous
//
#include <hip/hip_runtime.h>
#include <hip/hip_bf16.h>
#include <math.h>

// Layer_67637144978060 — chunked linear-RNN formulation, bf16 MFMA GEMMs.
// S_0 = W;  reads_t = S_t @ out_t;  S_{t+1} = e^lg S_t + v_t (x) wk_t;  W_new = S_T.
// Chunk C=1024 (NC=4). Parallel: rmsnorm, v-proj, transposes, intra-chunk scores,
// scores@v. Serial scan (4 steps x 2 GEMMs): R1 reads += e^{lg tc} out @ S_ch^T;
// S update (f32 master RMW + bf16 shadow).
// GEMM: 128x128 tile, BK=64, 4 waves (2x2), mfma_f32_16x16x32_bf16,
// global_load_lds width-16 + pre-swizzled source + XOR-swizzled ds_read (G4/#21).
// Workspace 180.4 MB (< round-1-proven 218 MB).

typedef __hip_bfloat16 bf16;
typedef short bf16x8 __attribute__((ext_vector_type(8)));
typedef float f32x4 __attribute__((ext_vector_type(4)));

#define TPB 256
#define LC 10
#define CH (1 << LC)   // chunk length 1024

__device__ __forceinline__ void gload_lds16(const void* g, void* l) {
  __builtin_amdgcn_global_load_lds(
      (const __attribute__((address_space(1))) unsigned int*)g,
      (__attribute__((address_space(3))) unsigned int*)l, 16, 0, 0);
}

enum { E_BF = 0, E_SCORES, E_READS, E_R1, E_UPD, E_FINAL };

struct MGP {
  const bf16 *A, *B;
  float *Cf; bf16 *Cb;
  const float *X; const bf16 *O;
  const float *dec;
  int K;
  int lda, ldb, ldc;
  long sAb, sBb, sCfb, sCbb, sOb, sCkb;
  int NC, aOff0, aStep, bOff0, bStep;
};

template<int MODE>
__global__ __launch_bounds__(TPB) void mg_k(MGP p) {
  __shared__ __align__(16) char ldsA[128 * 64 * 2];
  __shared__ __align__(16) char ldsB[128 * 64 * 2];
  const int tid = threadIdx.x;
  const int lane = tid & 63;
  const int w = tid >> 6;
  const int wr = w >> 1, wc = w & 1;
  const int z = blockIdx.z;
  const int b = z / p.NC, ch = z - b * p.NC;
  const int m0 = blockIdx.x * 128, n0 = blockIdx.y * 128;
  const float lg = -log1pf(expf(-p.dec[0]));   // log(sigmoid(decay))
  const bf16* Ab = p.A + b * p.sAb + ((long)(p.aOff0 + ch * p.aStep) + m0) * p.lda;
  const bf16* Bb = p.B + b * p.sBb + ((long)(p.bOff0 + ch * p.bStep) + n0) * p.ldb;

  f32x4 acc[4][4];
#pragma unroll
  for (int i = 0; i < 4; i++)
#pragma unroll
    for (int j = 0; j < 4; j++) acc[i][j] = (f32x4){0.f, 0.f, 0.f, 0.f};

  for (int k0 = 0; k0 < p.K; k0 += 64) {
    // ---- stage A/B tiles: linear LDS dest, pre-swizzled global source (#21) ----
#pragma unroll
    for (int c = 0; c < 4; c++) {
      const int o = w * 1024 + c * 4096 + lane * 16;        // linear LDS byte offset
      const int row = o >> 7;                               // tile row (128B = 64 bf16)
      const int cols = ((o & 127) ^ ((row & 7) << 4)) >> 1; // swizzled col (bf16 elems)
      gload_lds16(Ab + (long)row * p.lda + k0 + cols, ldsA + w * 1024 + c * 4096);
      gload_lds16(Bb + (long)row * p.ldb + k0 + cols, ldsB + w * 1024 + c * 4096);
    }
    __syncthreads();   // compiler drains vmcnt(0) before barrier
#pragma unroll
    for (int ks = 0; ks < 2; ks++) {
      bf16x8 af[4], bfr[4];
      const int cB = ks * 64 + ((lane >> 4) << 4);          // byte col of lane's k-slice
#pragma unroll
      for (int f = 0; f < 4; f++) {
        const int rA = wr * 64 + f * 16 + (lane & 15);
        af[f] = *(const bf16x8*)(ldsA + rA * 128 + (cB ^ ((rA & 7) << 4)));
        const int rB = wc * 64 + f * 16 + (lane & 15);
        bfr[f] = *(const bf16x8*)(ldsB + rB * 128 + (cB ^ ((rB & 7) << 4)));
      }
#pragma unroll
      for (int fm = 0; fm < 4; fm++)
#pragma unroll
        for (int fn = 0; fn < 4; fn++)
          acc[fm][fn] = __builtin_amdgcn_mfma_f32_16x16x32_bf16(af[fm], bfr[fn], acc[fm][fn], 0, 0, 0);
    }
    __syncthreads();
  }

  // ---- epilogue: C/D map col=lane&15, row=(lane>>4)*4+r [m89] ----
#pragma unroll
  for (int fm = 0; fm < 4; fm++) {
#pragma unroll
    for (int fn = 0; fn < 4; fn++) {
#pragma unroll
      for (int r = 0; r < 4; r++) {
        const int m = m0 + wr * 64 + fm * 16 + ((lane >> 4) << 2) + r;
        const int n = n0 + wc * 64 + fn * 16 + (lane & 15);
        const float vacc = acc[fm][fn][r];
        if constexpr (MODE == E_BF) {
          p.Cb[b * p.sCbb + (long)m * p.ldc + n] = __float2bfloat16(vacc);
        } else if constexpr (MODE == E_SCORES) {
          const float sv = (n < m) ? vacc * __expf(lg * (float)(m - 1 - n)) : 0.f;
          p.Cb[b * p.sCbb + ch * p.sCkb + (long)m * p.ldc + n] = __float2bfloat16(sv);
        } else if constexpr (MODE == E_READS) {
          p.Cb[b * p.sCbb + ch * p.sCkb + (long)m * p.ldc + n] = __float2bfloat16(vacc);
        } else if constexpr (MODE == E_R1) {
          bf16* c = p.Cb + b * p.sCbb + (long)m * p.ldc + n;
          *c = __float2bfloat16(__bfloat162float(*c) + __expf(lg * (float)m) * vacc);
        } else if constexpr (MODE == E_UPD) {
          const long idx = b * p.sCfb + (long)m * p.ldc + n;
          const float nv = __expf(lg * (float)p.K) * p.Cf[idx] + vacc;
          p.Cf[idx] = nv;
          p.Cb[b * p.sCbb + (long)m * p.ldc + n] = __float2bfloat16(nv);
        } else {  // E_FINAL
          const long idx = b * p.sCfb + (long)m * p.ldc + n;
          const float ov = __bfloat162float(p.O[b * p.sOb + (long)(m + 1) * p.ldc + n]);
          p.Cf[idx] = p.X[idx] + ov + 0.03f * vacc;
        }
      }
    }
  }
}

// RMSNorm: one block per row, writes bf16 into padded layout row t+1
__global__ __launch_bounds__(256) void rmsnorm_k(const float* __restrict__ x,
                                                 const float* __restrict__ g,
                                                 bf16* __restrict__ out_pad, int D, int T) {
  const long row = blockIdx.x;
  const long b = row / T, t = row - b * T;
  const float* xr = x + row * (long)D;
  bf16* orow = out_pad + (b * (long)(T + 1) + t + 1) * D;
  const int tid = threadIdx.x;
  const float4 xv = *(const float4*)&xr[tid * 4];
  float ss = xv.x * xv.x + xv.y * xv.y + xv.z * xv.z + xv.w * xv.w;
  for (int off = 32; off; off >>= 1) ss += __shfl_down(ss, off);
  __shared__ float sred[4];
  if ((tid & 63) == 0) sred[tid >> 6] = ss;
  __syncthreads();
  const float tot = sred[0] + sred[1] + sred[2] + sred[3];
  const float scale = rsqrtf(tot / (float)D + 1e-6f);
  const float4 gv = *(const float4*)&g[tid * 4];
  bf16 o4[4];
  o4[0] = __float2bfloat16(xv.x * scale * gv.x);
  o4[1] = __float2bfloat16(xv.y * scale * gv.y);
  o4[2] = __float2bfloat16(xv.z * scale * gv.z);
  o4[3] = __float2bfloat16(xv.w * scale * gv.w);
  *(ushort4*)(orow + tid * 4) = *(ushort4*)o4;
}

// zero the pad row (row 0) of each batch's padded out buffer
__global__ __launch_bounds__(256) void zpad_k(bf16* __restrict__ out_pad, int D, int T) {
  bf16* r = out_pad + (long)blockIdx.x * (T + 1) * D;
  ((ushort4*)r)[threadIdx.x] = make_ushort4(0, 0, 0, 0);
}

// W -> S (f32 master) + Sbf shadow
__global__ __launch_bounds__(256) void cvtW_k(const float* __restrict__ W, float* __restrict__ S,
                                              bf16* __restrict__ Sb, long n) {
  const long i = ((long)blockIdx.x * 256 + threadIdx.x) * 4;
  if (i >= n) return;
  const float4 v = *(const float4*)(W + i);
  *(float4*)(S + i) = v;
  bf16 o4[4] = {__float2bfloat16(v.x), __float2bfloat16(v.y),
                __float2bfloat16(v.z), __float2bfloat16(v.w)};
  *(ushort4*)(Sb + i) = *(ushort4*)o4;
}

// f32 -> bf16
__global__ __launch_bounds__(256) void f2bf_k(const float* __restrict__ s, bf16* __restrict__ d, long n) {
  const long i = ((long)blockIdx.x * 256 + threadIdx.x) * 4;
  if (i >= n) return;
  const float4 v = *(const float4*)(s + i);
  bf16 o4[4] = {__float2bfloat16(v.x), __float2bfloat16(v.y),
                __float2bfloat16(v.z), __float2bfloat16(v.w)};
  *(ushort4*)(d + i) = *(ushort4*)o4;
}

// transpose [T][D] -> [NC][D][CH]; WK=1: read padded src (wk shift) and fold decay weight
template<int WK>
__global__ __launch_bounds__(256) void tr_k(const bf16* __restrict__ src, bf16* __restrict__ dst,
                                            const float* __restrict__ dec, int D, int T, int NC) {
  __shared__ bf16 tl[32][33];
  const int b = blockIdx.z, d0 = blockIdx.x * 32, tg0 = blockIdx.y * 32;
  const int tx = threadIdx.x, ty = threadIdx.y;
  const float lg = -log1pf(expf(-dec[0]));
  for (int i = ty; i < 32; i += 8) {
    const int tg = tg0 + i;
    float val;
    if (WK)  // src row tg of padded buffer == out[tg-1] == wk[tg]
      val = __expf(lg * (float)(CH - 1 - (tg & (CH - 1)))) *
            __bfloat162float(src[((long)b * (T + 1) + tg) * D + d0 + tx]);
    else
      val = __bfloat162float(src[((long)b * T + tg) * D + d0 + tx]);
    tl[i][tx] = __float2bfloat16(val);
  }
  __syncthreads();
  const int ch = tg0 >> LC, tc0 = tg0 & (CH - 1);
  for (int i = ty; i < 32; i += 8)
    dst[(((long)b * NC + ch) * D + d0 + i) * CH + tc0 + tx] = tl[tx][i];
}

extern "C" void kernel_launch(void* const* d_in, const int* in_sizes, int n_in,
                              void* d_out, int out_size, void* d_ws, size_t ws_size,
                              hipStream_t stream) {
  const float* x     = (const float*)d_in[0];
  const float* W     = (const float*)d_in[1];
  const float* g     = (const float*)d_in[2];
  const float* Wpw   = (const float*)d_in[3];
  const float* Wpr   = (const float*)d_in[4];
  const float* decay = (const float*)d_in[5];

  const int D  = in_sizes[2];                 // 1024
  const int Bn = in_sizes[1] / (D * D);       // 4
  const int T  = in_sizes[0] / (Bn * D);      // 4096
  const int NC = T / CH;                      // 4 chunks
  const long TD = (long)T * D, DD = (long)D * D, PD = (long)(T + 1) * D;

  // workspace (all bf16): 180.4 MB total
  bf16* out_pad  = (bf16*)d_ws;                       // [B][T+1][D]
  bf16* vT       = out_pad + Bn * PD;                 // [B][NC][D][CH]
  bf16* wkTw     = vT + Bn * TD;                      // [B][NC][D][CH]
  bf16* scores   = wkTw + Bn * TD;                    // [B][NC][CH][CH]; also aliases v_rm
  bf16* Sbf      = scores + (long)Bn * NC * CH * CH;  // [B][D][D]
  bf16* Wpw_bf   = Sbf + Bn * DD;                     // [D][D]
  bf16* Wpr_bf   = Wpw_bf + DD;                       // [D][D]
  bf16* reads_bf = Wpr_bf + DD;                       // [B][T][D]
  bf16* v_rm     = scores;                            // [B][T][D] row-major v (pre-scores)

  float* y = (float*)d_out;                           // [B][T][D]
  float* S = y + Bn * TD;                             // [B][D][D] == W_new

  // 1) rmsnorm -> out_pad (bf16, row t+1); zero pad rows; init S; convert weights
  rmsnorm_k<<<Bn * T, D / 4, 0, stream>>>(x, g, out_pad, D, T);
  zpad_k<<<Bn, 256, 0, stream>>>(out_pad, D, T);
  cvtW_k<<<(int)(Bn * DD / 1024), 256, 0, stream>>>(W, S, Sbf, Bn * DD);
  f2bf_k<<<(int)(DD / 1024), 256, 0, stream>>>(Wpw, Wpw_bf, DD);
  f2bf_k<<<(int)(DD / 1024), 256, 0, stream>>>(Wpr, Wpr_bf, DD);

  // 2) v_rm = out @ Wp_w^T (bf16 row-major)
  {
    MGP p{}; p.dec = decay;
    p.A = out_pad; p.lda = D; p.sAb = PD; p.aOff0 = 1;
    p.B = Wpw_bf;  p.ldb = D;
    p.Cb = v_rm; p.ldc = D; p.sCbb = TD;
    p.K = D; p.NC = 1;
    mg_k<E_BF><<<dim3(T / 128, D / 128, Bn), TPB, 0, stream>>>(p);
  }
  // 3) vT = per-chunk transpose of v_rm;  wkTw = per-chunk weighted transpose of wk
  tr_k<0><<<dim3(D / 32, T / 32, Bn), dim3(32, 8), 0, stream>>>(v_rm, vT, decay, D, T, NC);
  tr_k<1><<<dim3(D / 32, T / 32, Bn), dim3(32, 8), 0, stream>>>(out_pad, wkTw, decay, D, T, NC);
  // 4) intra-chunk scores (overwrites v_rm region — v already transposed)
  {
    MGP p{}; p.dec = decay;
    p.A = out_pad; p.lda = D; p.sAb = PD; p.aOff0 = 1; p.aStep = CH;
    p.B = out_pad; p.ldb = D; p.sBb = PD; p.bOff0 = 0; p.bStep = CH;
    p.Cb = scores; p.ldc = CH; p.sCbb = (long)NC * CH * CH; p.sCkb = (long)CH * CH;
    p.K = D; p.NC = NC;
    mg_k<E_SCORES><<<dim3(CH / 128, CH / 128, Bn * NC), TPB, 0, stream>>>(p);
  }
  // 5) reads (intra) = scores @ v  (bf16 out)
  {
    MGP p{}; p.dec = decay;
    p.A = scores; p.lda = CH; p.sAb = (long)Bn ? (long)NC * CH * CH : 0; p.aStep = CH;
    p.B = vT;     p.ldb = CH; p.sBb = TD; p.bStep = D;
    p.Cb = reads_bf; p.ldc = D; p.sCbb = TD; p.sCkb = (long)CH * D;
    p.K = CH; p.NC = NC;
    // fix accidental ternary: sAb is NC*CH*CH
    p.sAb = (long)NC * CH * CH;
    mg_k<E_READS><<<dim3(CH / 128, D / 128, Bn * NC), TPB, 0, stream>>>(p);
  }
  // 6) serial scan: 4 steps x {R1, UPD}
  for (int ch = 0; ch < NC; ch++) {
    { // reads[t0+tc] += e^{lg tc} * out @ S_ch^T
      MGP p{}; p.dec = decay;
      p.A = out_pad; p.lda = D; p.sAb = PD; p.aOff0 = ch * CH + 1;
      p.B = Sbf;     p.ldb = D; p.sBb = DD;
      p.Cb = reads_bf + (long)ch * CH * D; p.ldc = D; p.sCbb = TD;
      p.K = D; p.NC = 1;
      mg_k<E_R1><<<dim3(CH / 128, D / 128, Bn), TPB, 0, stream>>>(p);
    }
    { // S = e^{lg CH} S + vT_ch @ wkTw_ch^T (over tc); f32 master + bf16 shadow
      MGP p{}; p.dec = decay;
      p.A = vT;   p.lda = CH; p.sAb = TD; p.aOff0 = ch * D;
      p.B = wkTw; p.ldb = CH; p.sBb = TD; p.bOff0 = ch * D;
      p.Cf = S;   p.ldc = D; p.sCfb = DD;
      p.Cb = Sbf; p.sCbb = DD;
      p.K = CH; p.NC = 1;
      mg_k<E_UPD><<<dim3(D / 128, D / 128, Bn), TPB, 0, stream>>>(p);
    }
  }
  // 7) y = x + out + 0.03 * reads @ Wp_r^T
  {
    MGP p{}; p.dec = decay;
    p.A = reads_bf; p.lda = D; p.sAb = TD;
    p.B = Wpr_bf;   p.ldb = D;
    p.Cf = y; p.ldc = D; p.sCfb = TD;
    p.X = x; p.O = out_pad; p.sOb = PD;
    p.K = D; p.NC = 1;
    mg_k<E_FINAL><<<dim3(T / 128, D / 128, Bn), TPB, 0, stream>>>(p);
  }
}

// Round 9
// 594.972 us; speedup vs baseline: 5.5989x; 1.2527x over previous
//
#include <hip/hip_runtime.h>
#include <hip/hip_bf16.h>
#include <math.h>

// Layer_67637144978060 — chunked linear-RNN, bf16 MFMA GEMMs, PARALLEL scan.
// S_0 = W;  reads_t = S_t @ out_t;  S_{t+1} = e^lg S_t + v_t (x) wk_t;  W_new = S_T.
// Chunk CH=1024 (NC=4). All-parallel: rmsnorm, v-proj, transposes,
// P_ch = vT_ch @ wkTw_ch^T (all chunks, one launch), intra-chunk scores
// (lower-triangle blocks only), reads_intra = scores @ v (K truncated at diag),
// Horner combine S_ch = a^ch W + sum a^{...} P_j (+ W_new), R1 (all chunks, one
// launch): reads += e^{lg tc} out_ch @ S_ch^T, final projection.
// GEMM: 128x128 tile, BK=64, 4 waves (2x2), mfma_f32_16x16x32_bf16,
// global_load_lds width-16 + pre-swizzled source + XOR-swizzled ds_read (G4/#21).
// Workspace 196.1 MB (< round-1-proven 218 MB). Sch aliases scores (stream-ordered).

typedef __hip_bfloat16 bf16;
typedef short bf16x8 __attribute__((ext_vector_type(8)));
typedef float f32x4 __attribute__((ext_vector_type(4)));

#define TPB 256
#define LC 10
#define CH (1 << LC)   // chunk length 1024

__device__ __forceinline__ void gload_lds16(const void* g, void* l) {
  __builtin_amdgcn_global_load_lds(
      (const __attribute__((address_space(1))) unsigned int*)g,
      (__attribute__((address_space(3))) unsigned int*)l, 16, 0, 0);
}

enum { E_BF = 0, E_SCORES, E_READS, E_R1, E_FINAL };

struct MGP {
  const bf16 *A, *B;
  float *Cf; bf16 *Cb;
  const float *X; const bf16 *O;
  const float *dec;
  int K;
  int lda, ldb, ldc;
  long sAb, sBb, sCfb, sCbb, sOb, sCkb;
  int NC, aOff0, aStep, bOff0, bStep;
  int tri;   // 1: truncate K-loop at m0+128 (lower-triangular A)
};

template<int MODE>
__global__ __launch_bounds__(TPB) void mg_k(MGP p) {
  __shared__ __align__(16) char ldsA[128 * 64 * 2];
  __shared__ __align__(16) char ldsB[128 * 64 * 2];
  const int tid = threadIdx.x;
  const int lane = tid & 63;
  const int w = tid >> 6;
  const int wr = w >> 1, wc = w & 1;
  const int z = blockIdx.z;
  const int b = z / p.NC, ch = z - b * p.NC;
  const int m0 = blockIdx.x * 128, n0 = blockIdx.y * 128;
  if constexpr (MODE == E_SCORES) {
    if (n0 > m0) return;               // fully-masked block (n >= m ⇒ mask 0)
  }
  const float lg = -log1pf(expf(-p.dec[0]));   // log(sigmoid(decay))
  const bf16* Ab = p.A + b * p.sAb + ((long)(p.aOff0 + ch * p.aStep) + m0) * p.lda;
  const bf16* Bb = p.B + b * p.sBb + ((long)(p.bOff0 + ch * p.bStep) + n0) * p.ldb;

  f32x4 acc[4][4];
#pragma unroll
  for (int i = 0; i < 4; i++)
#pragma unroll
    for (int j = 0; j < 4; j++) acc[i][j] = (f32x4){0.f, 0.f, 0.f, 0.f};

  const int Kend = p.tri ? (m0 + 128 < p.K ? m0 + 128 : p.K) : p.K;
  for (int k0 = 0; k0 < Kend; k0 += 64) {
    // ---- stage A/B tiles: linear LDS dest, pre-swizzled global source (#21) ----
#pragma unroll
    for (int c = 0; c < 4; c++) {
      const int o = w * 1024 + c * 4096 + lane * 16;        // linear LDS byte offset
      const int row = o >> 7;                               // tile row (128B = 64 bf16)
      const int cols = ((o & 127) ^ ((row & 7) << 4)) >> 1; // swizzled col (bf16 elems)
      gload_lds16(Ab + (long)row * p.lda + k0 + cols, ldsA + w * 1024 + c * 4096);
      gload_lds16(Bb + (long)row * p.ldb + k0 + cols, ldsB + w * 1024 + c * 4096);
    }
    __syncthreads();   // compiler drains vmcnt(0) before barrier
#pragma unroll
    for (int ks = 0; ks < 2; ks++) {
      bf16x8 af[4], bfr[4];
      const int cB = ks * 64 + ((lane >> 4) << 4);          // byte col of lane's k-slice
#pragma unroll
      for (int f = 0; f < 4; f++) {
        const int rA = wr * 64 + f * 16 + (lane & 15);
        af[f] = *(const bf16x8*)(ldsA + rA * 128 + (cB ^ ((rA & 7) << 4)));
        const int rB = wc * 64 + f * 16 + (lane & 15);
        bfr[f] = *(const bf16x8*)(ldsB + rB * 128 + (cB ^ ((rB & 7) << 4)));
      }
#pragma unroll
      for (int fm = 0; fm < 4; fm++)
#pragma unroll
        for (int fn = 0; fn < 4; fn++)
          acc[fm][fn] = __builtin_amdgcn_mfma_f32_16x16x32_bf16(af[fm], bfr[fn], acc[fm][fn], 0, 0, 0);
    }
    __syncthreads();
  }

  // ---- epilogue: C/D map col=lane&15, row=(lane>>4)*4+r [m89] ----
#pragma unroll
  for (int fm = 0; fm < 4; fm++) {
#pragma unroll
    for (int fn = 0; fn < 4; fn++) {
#pragma unroll
      for (int r = 0; r < 4; r++) {
        const int m = m0 + wr * 64 + fm * 16 + ((lane >> 4) << 2) + r;
        const int n = n0 + wc * 64 + fn * 16 + (lane & 15);
        const float vacc = acc[fm][fn][r];
        if constexpr (MODE == E_BF) {
          p.Cb[b * p.sCbb + (long)m * p.ldc + n] = __float2bfloat16(vacc);
        } else if constexpr (MODE == E_SCORES) {
          const float sv = (n < m) ? vacc * __expf(lg * (float)(m - 1 - n)) : 0.f;
          p.Cb[b * p.sCbb + ch * p.sCkb + (long)m * p.ldc + n] = __float2bfloat16(sv);
        } else if constexpr (MODE == E_READS) {
          p.Cb[b * p.sCbb + ch * p.sCkb + (long)m * p.ldc + n] = __float2bfloat16(vacc);
        } else if constexpr (MODE == E_R1) {
          bf16* c = p.Cb + b * p.sCbb + ch * p.sCkb + (long)m * p.ldc + n;
          *c = __float2bfloat16(__bfloat162float(*c) + __expf(lg * (float)m) * vacc);
        } else {  // E_FINAL
          const long idx = b * p.sCfb + (long)m * p.ldc + n;
          const float ov = __bfloat162float(p.O[b * p.sOb + (long)(m + 1) * p.ldc + n]);
          p.Cf[idx] = p.X[idx] + ov + 0.03f * vacc;
        }
      }
    }
  }
}

// RMSNorm: one block per row, writes bf16 into padded layout row t+1
__global__ __launch_bounds__(256) void rmsnorm_k(const float* __restrict__ x,
                                                 const float* __restrict__ g,
                                                 bf16* __restrict__ out_pad, int D, int T) {
  const long row = blockIdx.x;
  const long b = row / T, t = row - b * T;
  const float* xr = x + row * (long)D;
  bf16* orow = out_pad + (b * (long)(T + 1) + t + 1) * D;
  const int tid = threadIdx.x;
  const float4 xv = *(const float4*)&xr[tid * 4];
  float ss = xv.x * xv.x + xv.y * xv.y + xv.z * xv.z + xv.w * xv.w;
  for (int off = 32; off; off >>= 1) ss += __shfl_down(ss, off);
  __shared__ float sred[4];
  if ((tid & 63) == 0) sred[tid >> 6] = ss;
  __syncthreads();
  const float tot = sred[0] + sred[1] + sred[2] + sred[3];
  const float scale = rsqrtf(tot / (float)D + 1e-6f);
  const float4 gv = *(const float4*)&g[tid * 4];
  bf16 o4[4];
  o4[0] = __float2bfloat16(xv.x * scale * gv.x);
  o4[1] = __float2bfloat16(xv.y * scale * gv.y);
  o4[2] = __float2bfloat16(xv.z * scale * gv.z);
  o4[3] = __float2bfloat16(xv.w * scale * gv.w);
  *(ushort4*)(orow + tid * 4) = *(ushort4*)o4;
}

// zero the pad row (row 0) of each batch's padded out buffer
__global__ __launch_bounds__(256) void zpad_k(bf16* __restrict__ out_pad, int D, int T) {
  bf16* r = out_pad + (long)blockIdx.x * (T + 1) * D;
  ((ushort4*)r)[threadIdx.x] = make_ushort4(0, 0, 0, 0);
}

// f32 -> bf16
__global__ __launch_bounds__(256) void f2bf_k(const float* __restrict__ s, bf16* __restrict__ d, long n) {
  const long i = ((long)blockIdx.x * 256 + threadIdx.x) * 4;
  if (i >= n) return;
  const float4 v = *(const float4*)(s + i);
  bf16 o4[4] = {__float2bfloat16(v.x), __float2bfloat16(v.y),
                __float2bfloat16(v.z), __float2bfloat16(v.w)};
  *(ushort4*)(d + i) = *(ushort4*)o4;
}

__device__ __forceinline__ float4 load_bf4(const bf16* p) {
  const ushort4 u = *(const ushort4*)p;
  float4 f;
  f.x = __bfloat162float(*(const bf16*)&u.x);
  f.y = __bfloat162float(*(const bf16*)&u.y);
  f.z = __bfloat162float(*(const bf16*)&u.z);
  f.w = __bfloat162float(*(const bf16*)&u.w);
  return f;
}
__device__ __forceinline__ void store_bf4(bf16* p, float4 f) {
  bf16 o4[4] = {__float2bfloat16(f.x), __float2bfloat16(f.y),
                __float2bfloat16(f.z), __float2bfloat16(f.w)};
  *(ushort4*)p = *(ushort4*)o4;
}

// Horner combine: S_ch = a^ch W + sum_{j<ch} a^{ch-1-j} P_j ; W_new = S_NC (f32)
__global__ __launch_bounds__(256) void comb_k(const float* __restrict__ W,
                                              const bf16* __restrict__ P,
                                              bf16* __restrict__ Sch,
                                              float* __restrict__ Wn,
                                              const float* __restrict__ dec,
                                              long DDl, int NC) {
  const long i = ((long)blockIdx.x * 256 + threadIdx.x) * 4;
  const int b = (int)(i / DDl);
  const long e = i - (long)b * DDl;
  const float lg = -log1pf(expf(-dec[0]));
  const float a = __expf(lg * (float)CH);
  float4 s = *(const float4*)(W + i);
  store_bf4(Sch + ((long)b * NC) * DDl + e, s);            // S_0 = W
  for (int ch = 0; ch < NC; ch++) {
    const float4 pp = load_bf4(P + ((long)b * NC + ch) * DDl + e);
    s.x = a * s.x + pp.x;  s.y = a * s.y + pp.y;
    s.z = a * s.z + pp.z;  s.w = a * s.w + pp.w;
    if (ch + 1 < NC) store_bf4(Sch + ((long)b * NC + ch + 1) * DDl + e, s);
  }
  *(float4*)(Wn + i) = s;                                  // W_new = S_NC
}

// transpose [T][D] -> [NC][D][CH]; WK=1: read padded src (wk shift) and fold decay weight
template<int WK>
__global__ __launch_bounds__(256) void tr_k(const bf16* __restrict__ src, bf16* __restrict__ dst,
                                            const float* __restrict__ dec, int D, int T, int NC) {
  __shared__ bf16 tl[32][33];
  const int b = blockIdx.z, d0 = blockIdx.x * 32, tg0 = blockIdx.y * 32;
  const int tx = threadIdx.x, ty = threadIdx.y;
  const float lg = -log1pf(expf(-dec[0]));
  for (int i = ty; i < 32; i += 8) {
    const int tg = tg0 + i;
    float val;
    if (WK)  // src row tg of padded buffer == out[tg-1] == wk[tg]
      val = __expf(lg * (float)(CH - 1 - (tg & (CH - 1)))) *
            __bfloat162float(src[((long)b * (T + 1) + tg) * D + d0 + tx]);
    else
      val = __bfloat162float(src[((long)b * T + tg) * D + d0 + tx]);
    tl[i][tx] = __float2bfloat16(val);
  }
  __syncthreads();
  const int ch = tg0 >> LC, tc0 = tg0 & (CH - 1);
  for (int i = ty; i < 32; i += 8)
    dst[(((long)b * NC + ch) * D + d0 + i) * CH + tc0 + tx] = tl[tx][i];
}

extern "C" void kernel_launch(void* const* d_in, const int* in_sizes, int n_in,
                              void* d_out, int out_size, void* d_ws, size_t ws_size,
                              hipStream_t stream) {
  const float* x     = (const float*)d_in[0];
  const float* W     = (const float*)d_in[1];
  const float* g     = (const float*)d_in[2];
  const float* Wpw   = (const float*)d_in[3];
  const float* Wpr   = (const float*)d_in[4];
  const float* decay = (const float*)d_in[5];

  const int D  = in_sizes[2];                 // 1024
  const int Bn = in_sizes[1] / (D * D);       // 4
  const int T  = in_sizes[0] / (Bn * D);      // 4096
  const int NC = T / CH;                      // 4 chunks
  const long TD = (long)T * D, DD = (long)D * D, PD = (long)(T + 1) * D;

  // workspace (all bf16): 196.1 MB total
  bf16* out_pad  = (bf16*)d_ws;                       // [B][T+1][D]
  bf16* vT       = out_pad + Bn * PD;                 // [B][NC][D][CH]
  bf16* wkTw     = vT + Bn * TD;                      // [B][NC][D][CH]
  bf16* scores   = wkTw + Bn * TD;                    // [B][NC][CH][CH]; aliases v_rm & Sch
  bf16* P_bf     = scores + (long)Bn * NC * CH * CH;  // [B][NC][D][D]
  bf16* Wpw_bf   = P_bf + (long)Bn * NC * DD;         // [D][D]
  bf16* Wpr_bf   = Wpw_bf + DD;                       // [D][D]
  bf16* reads_bf = Wpr_bf + DD;                       // [B][T][D]
  bf16* v_rm     = scores;                            // [B][T][D] row-major v (pre-scores)
  bf16* Sch      = scores;                            // [B][NC][D][D] (post-E_READS)

  float* y = (float*)d_out;                           // [B][T][D]
  float* S = y + Bn * TD;                             // [B][D][D] == W_new

  // 1) rmsnorm -> out_pad (bf16, row t+1); zero pad rows; convert weights
  rmsnorm_k<<<Bn * T, D / 4, 0, stream>>>(x, g, out_pad, D, T);
  zpad_k<<<Bn, 256, 0, stream>>>(out_pad, D, T);
  f2bf_k<<<(int)(DD / 1024), 256, 0, stream>>>(Wpw, Wpw_bf, DD);
  f2bf_k<<<(int)(DD / 1024), 256, 0, stream>>>(Wpr, Wpr_bf, DD);

  // 2) v_rm = out @ Wp_w^T (bf16 row-major)
  {
    MGP p{}; p.dec = decay;
    p.A = out_pad; p.lda = D; p.sAb = PD; p.aOff0 = 1;
    p.B = Wpw_bf;  p.ldb = D;
    p.Cb = v_rm; p.ldc = D; p.sCbb = TD;
    p.K = D; p.NC = 1;
    mg_k<E_BF><<<dim3(T / 128, D / 128, Bn), TPB, 0, stream>>>(p);
  }
  // 3) vT = per-chunk transpose of v_rm;  wkTw = per-chunk weighted transpose of wk
  tr_k<0><<<dim3(D / 32, T / 32, Bn), dim3(32, 8), 0, stream>>>(v_rm, vT, decay, D, T, NC);
  tr_k<1><<<dim3(D / 32, T / 32, Bn), dim3(32, 8), 0, stream>>>(out_pad, wkTw, decay, D, T, NC);
  // 4) P_ch = vT_ch @ wkTw_ch^T  (all chunks in parallel, bf16 out)
  {
    MGP p{}; p.dec = decay;
    p.A = vT;   p.lda = CH; p.sAb = TD; p.aStep = D;
    p.B = wkTw; p.ldb = CH; p.sBb = TD; p.bStep = D;
    p.Cb = P_bf; p.ldc = D; p.sCbb = (long)NC * DD; p.sCkb = DD;
    p.K = CH; p.NC = NC;
    mg_k<E_READS><<<dim3(D / 128, D / 128, Bn * NC), TPB, 0, stream>>>(p);
  }
  // 5) intra-chunk scores (lower-triangle blocks only; overwrites v_rm region)
  {
    MGP p{}; p.dec = decay;
    p.A = out_pad; p.lda = D; p.sAb = PD; p.aOff0 = 1; p.aStep = CH;
    p.B = out_pad; p.ldb = D; p.sBb = PD; p.bOff0 = 0; p.bStep = CH;
    p.Cb = scores; p.ldc = CH; p.sCbb = (long)NC * CH * CH; p.sCkb = (long)CH * CH;
    p.K = D; p.NC = NC;
    mg_k<E_SCORES><<<dim3(CH / 128, CH / 128, Bn * NC), TPB, 0, stream>>>(p);
  }
  // 6) reads (intra) = scores @ v  (K truncated at diagonal)
  {
    MGP p{}; p.dec = decay;
    p.A = scores; p.lda = CH; p.sAb = (long)NC * CH * CH; p.aStep = CH;
    p.B = vT;     p.ldb = CH; p.sBb = TD; p.bStep = D;
    p.Cb = reads_bf; p.ldc = D; p.sCbb = TD; p.sCkb = (long)CH * D;
    p.K = CH; p.NC = NC; p.tri = 1;
    mg_k<E_READS><<<dim3(CH / 128, D / 128, Bn * NC), TPB, 0, stream>>>(p);
  }
  // 7) Horner combine: Sch (bf16, aliases scores region — scores now dead) + W_new (f32)
  comb_k<<<(int)(Bn * DD / 1024), 256, 0, stream>>>(W, P_bf, Sch, S, decay, DD, NC);
  // 8) R1 (all chunks in parallel): reads[ch*CH+tc] += e^{lg tc} * out_ch @ S_ch^T
  {
    MGP p{}; p.dec = decay;
    p.A = out_pad; p.lda = D; p.sAb = PD; p.aOff0 = 1; p.aStep = CH;
    p.B = Sch;     p.ldb = D; p.sBb = (long)NC * DD; p.bStep = D;
    p.Cb = reads_bf; p.ldc = D; p.sCbb = TD; p.sCkb = (long)CH * D;
    p.K = D; p.NC = NC;
    mg_k<E_R1><<<dim3(CH / 128, D / 128, Bn * NC), TPB, 0, stream>>>(p);
  }
  // 9) y = x + out + 0.03 * reads @ Wp_r^T
  {
    MGP p{}; p.dec = decay;
    p.A = reads_bf; p.lda = D; p.sAb = TD;
    p.B = Wpr_bf;   p.ldb = D;
    p.Cf = y; p.ldc = D; p.sCfb = TD;
    p.X = x; p.O = out_pad; p.sOb = PD;
    p.K = D; p.NC = 1;
    mg_k<E_FINAL><<<dim3(T / 128, D / 128, Bn), TPB, 0, stream>>>(p);
  }
}